// Round 7
// baseline (1071.140 us; speedup 1.0000x reference)
//
#include <hip/hip_runtime.h>
#include <hip/hip_bf16.h>
#include <cstdint>

#define T_TOK 2048
#define HDIM  2048
#define IDIM  8192
#define NEXP  8

typedef short s16x8 __attribute__((ext_vector_type(8)));
typedef float f32x4 __attribute__((ext_vector_type(4)));
typedef uint32_t u32x2 __attribute__((ext_vector_type(2)));
typedef const __attribute__((address_space(1))) uint32_t gbl_u32;
typedef __attribute__((address_space(3))) uint32_t lds_u32;

__device__ __forceinline__ unsigned short f2b(float f) {
    union { float f; unsigned u; } c; c.f = f;
    unsigned r = (c.u + 0x7fffu + ((c.u >> 16) & 1u)) >> 16;
    return (unsigned short)r;
}

// packed bf16(a) | bf16(b)<<16, RNE (compiler emits v_cvt_pk_bf16_f32)
__device__ __forceinline__ uint32_t pk_bf16(float a, float b) {
    union { __hip_bfloat162 h; uint32_t u; } c;
    c.h = __float22bfloat162_rn(make_float2(a, b));
    return c.u;
}

__device__ __forceinline__ float gelu_tanh(float v) {
    float u = 0.7978845608028654f * (v + 0.044715f * v * v * v);
    return 0.5f * v * (1.0f + tanhf(u));
}

// ---------------- K1: gate (logits fp32, softmax, top-2) + cast x -> bf16 ----
__global__ __launch_bounds__(256) void k_gate(
    const float* __restrict__ x, const float* __restrict__ gw,
    const float* __restrict__ gb, const float* __restrict__ alpha,
    unsigned short* __restrict__ xb, int* __restrict__ counts,
    int* __restrict__ top_e, float* __restrict__ top_g)
{
    const int wave = threadIdx.x >> 6;
    const int lane = threadIdx.x & 63;
    const int t = blockIdx.x * 4 + wave;
    if (t >= T_TOK) return;

    float acc[8];
    #pragma unroll
    for (int e = 0; e < 8; e++) acc[e] = 0.f;

    const float* xrow = x + (size_t)t * HDIM;
    unsigned short* xbrow = xb + (size_t)t * HDIM;

    #pragma unroll
    for (int c = 0; c < 8; c++) {
        const int h0 = c * 256 + lane * 4;
        const float4 xv = *reinterpret_cast<const float4*>(xrow + h0);
        ushort4 u;
        u.x = f2b(xv.x); u.y = f2b(xv.y); u.z = f2b(xv.z); u.w = f2b(xv.w);
        *reinterpret_cast<ushort4*>(xbrow + h0) = u;
        const float xs[4] = {xv.x, xv.y, xv.z, xv.w};
        #pragma unroll
        for (int r = 0; r < 4; r++) {
            const float4 g0 = *reinterpret_cast<const float4*>(gw + (size_t)(h0 + r) * 8);
            const float4 g1 = *reinterpret_cast<const float4*>(gw + (size_t)(h0 + r) * 8 + 4);
            acc[0] += xs[r] * g0.x; acc[1] += xs[r] * g0.y;
            acc[2] += xs[r] * g0.z; acc[3] += xs[r] * g0.w;
            acc[4] += xs[r] * g1.x; acc[5] += xs[r] * g1.y;
            acc[6] += xs[r] * g1.z; acc[7] += xs[r] * g1.w;
        }
    }
    #pragma unroll
    for (int e = 0; e < 8; e++) {
        #pragma unroll
        for (int off = 32; off > 0; off >>= 1)
            acc[e] += __shfl_xor(acc[e], off);
        acc[e] += gb[e];
    }
    float m = acc[0];
    #pragma unroll
    for (int e = 1; e < 8; e++) m = fmaxf(m, acc[e]);
    float Z = 0.f;
    #pragma unroll
    for (int e = 0; e < 8; e++) Z += expf(acc[e] - m);
    int e0 = 0; float b0 = acc[0];
    #pragma unroll
    for (int e = 1; e < 8; e++) if (acc[e] > b0) { b0 = acc[e]; e0 = e; }
    int e1 = -1; float b1 = -1e30f;
    #pragma unroll
    for (int e = 0; e < 8; e++) if (e != e0 && acc[e] > b1) { b1 = acc[e]; e1 = e; }

    if (lane == 0) {
        const float s0 = expf(b0 - m) / Z * alpha[e0];
        const float s1 = expf(b1 - m) / Z * alpha[e1];
        top_e[2 * t]     = e0; top_e[2 * t + 1] = e1;
        top_g[2 * t]     = s0; top_g[2 * t + 1] = s1;
        atomicAdd(&counts[e0], 1);
        atomicAdd(&counts[e1], 1);
    }
}

// ---------------- K2: exclusive scan of 8 counts -----------------------------
__global__ void k_scan(const int* __restrict__ counts, int* __restrict__ offsets,
                       int* __restrict__ cursors)
{
    if (threadIdx.x == 0) {
        int off = 0;
        for (int e = 0; e < NEXP; e++) {
            offsets[e] = off; cursors[e] = off; off += counts[e];
        }
    }
}

// ---------------- K3: append tokens to per-expert compact slot lists ---------
__global__ __launch_bounds__(256) void k_append(
    const int* __restrict__ top_e, const float* __restrict__ top_g,
    int* __restrict__ cursors, int* __restrict__ slot_token,
    float* __restrict__ slot_gate, int* __restrict__ tok2slot)
{
    const int t = blockIdx.x * 256 + threadIdx.x;
    if (t >= T_TOK) return;
    #pragma unroll
    for (int k = 0; k < 2; k++) {
        const int e = top_e[2 * t + k];
        const int slot = atomicAdd(&cursors[e], 1);
        slot_token[slot] = t;
        slot_gate[slot]  = top_g[2 * t + k];
        tok2slot[2 * t + k] = slot;
    }
}

// ---------------- K4/K5: high-TLP fused-convert MFMA GEMM -------------------
// BM=128, BK=32, single-buffered, 2 barriers/K-step (m97 regime, small LDS).
// A: bf16 rows via global_load_lds, [128][32] linear, 4-chunk XOR involution.
// B: fp32 [K][N] weights, coalesced float4, cvt_pk, ds_write into [n][20dw]
//    with chunk ^= (n>>3)&3  (4-way write conflicts; b128 reads at floor).
// FC1: BN=128, 4 waves 2x2 (64x64 each).  FC2: BN=64, 4 waves 4x1 (32x64).
template<bool FC1>
__global__ __launch_bounds__(256, 4) void k_gemm(
    const unsigned short* __restrict__ Abase,
    const float* __restrict__ W,
    const float* __restrict__ bias,
    const int* __restrict__ counts,
    const int* __restrict__ offsets,
    const int* __restrict__ slot_token,
    const float* __restrict__ slot_gate,
    unsigned short* __restrict__ out_bf,
    float* __restrict__ out_f)
{
    constexpr int N  = FC1 ? IDIM : HDIM;
    constexpr int K  = FC1 ? HDIM : IDIM;
    constexpr int BN = FC1 ? 128 : 64;
    constexpr int NT = N / BN;
    constexpr int MT = T_TOK / 128;
    constexpr int NK = K / 32;
    constexpr int MI = FC1 ? 4 : 2;
    constexpr int KL = FC1 ? 4 : 2;

    // bijective XCD swizzle (nwg % 8 == 0), m fastest: weight panel L2-shared.
    constexpr int nwg = NEXP * NT * MT;
    constexpr int cpx = nwg >> 3;
    const int bid = blockIdx.x;
    const int wg  = (bid & 7) * cpx + (bid >> 3);
    const int e   = wg / (NT * MT);
    const int rem = wg - e * (NT * MT);
    const int nb  = rem / MT;
    const int mb  = rem - nb * MT;

    const int cnt = counts[e];
    const int m0  = mb * 128;
    if (m0 >= cnt) return;
    const int moff  = offsets[e];
    const int n0    = nb * BN;
    const int slot0 = moff + m0;

    __shared__ short    As[128 * 32];   // 8 KB
    __shared__ uint32_t Bs[BN * 20];    // 10/5 KB

    const int tid  = threadIdx.x;
    const int lane = tid & 63, wave = tid >> 6;
    const int lo = lane & 15, hi = lane >> 4;
    const int wmb = FC1 ? (wave >> 1) * 64 : wave * 32;
    const int wnb = FC1 ? (wave & 1) * 64 : 0;

    // A staging: rows (tid>>2)+{0,64}, 16B chunk tid&3, involution ch^=(row&3)
    const unsigned short* asrc[2];
    #pragma unroll
    for (int it = 0; it < 2; it++) {
        const int row = (tid >> 2) + it * 64;
        int tok;
        if (FC1) tok = (m0 + row < cnt) ? slot_token[moff + m0 + row] : 0;
        else     tok = slot0 + ((m0 + row < cnt) ? row : 0);
        asrc[it] = Abase + (size_t)tok * K;
    }
    const int achunk = tid & 3;
    const float* wcol = W + (size_t)e * K * N + n0;

    // B load geometry
    const int Q  = FC1 ? (tid >> 5) : ((tid >> 4) & 7);
    const int rh = FC1 ? 0 : (tid >> 7);
    const int n4 = FC1 ? (tid & 31) * 4 : (tid & 15) * 4;
    const int k0 = 4 * Q + 2 * rh;

    f32x4 acc[MI][4];
    #pragma unroll
    for (int i = 0; i < MI; i++)
        #pragma unroll
        for (int j = 0; j < 4; j++) acc[i][j] = (f32x4)0.f;

    for (int t = 0; t < NK; t++) {
        const int kk = t * 32;
        // ---- A: global -> LDS direct ----
        #pragma unroll
        for (int it = 0; it < 2; it++) {
            const int row = (tid >> 2) + it * 64;
            const int sc  = achunk ^ (row & 3);
            __builtin_amdgcn_global_load_lds(
                (gbl_u32*)(asrc[it] + kk + sc * 8),
                (lds_u32*)(As + (tid + it * 256) * 8), 16, 0, 0);
        }
        // ---- B: coalesced loads ----
        float w[KL][4];
        #pragma unroll
        for (int r = 0; r < KL; r++) {
            const float4 v = *reinterpret_cast<const float4*>(
                wcol + (size_t)(kk + k0 + r) * N + n4);
            w[r][0] = v.x; w[r][1] = v.y; w[r][2] = v.z; w[r][3] = v.w;
        }
        // ---- B: pack + swizzled LDS write ----
        #pragma unroll
        for (int dn = 0; dn < 4; dn++) {
            const int n  = n4 + dn;
            const int gg = (n >> 3) & 3;
            if (FC1) {
                const int q = 2 * Q;             // chunk Q>>1, pos q&3 (even)
                const int dw = n * 20 + (((Q >> 1) ^ gg) << 2) + (q & 3);
                u32x2 pk;
                pk.x = pk_bf16(w[0][dn], w[1][dn]);
                pk.y = pk_bf16(w[2][dn], w[3][dn]);
                *reinterpret_cast<u32x2*>(Bs + dw) = pk;
            } else {
                const int q = 2 * Q + rh;
                const int dw = n * 20 + (((q >> 2) ^ gg) << 2) + (q & 3);
                Bs[dw] = pk_bf16(w[0][dn], w[1][dn]);
            }
        }
        __syncthreads();   // drains glds; Bs visible
        // ---- fragments + MFMA ----
        s16x8 af[MI], bfr[4];
        #pragma unroll
        for (int i = 0; i < MI; i++) {
            const int arow = wmb + i * 16 + lo;
            const int ch = hi ^ (arow & 3);
            af[i] = *reinterpret_cast<const s16x8*>(As + arow * 32 + ch * 8);
        }
        #pragma unroll
        for (int j = 0; j < 4; j++) {
            const int coln = wnb + j * 16 + lo;
            const int gg = (coln >> 3) & 3;
            bfr[j] = *reinterpret_cast<const s16x8*>(Bs + coln * 20 + ((hi ^ gg) << 2));
        }
        __builtin_amdgcn_s_setprio(1);
        #pragma unroll
        for (int i = 0; i < MI; i++)
            #pragma unroll
            for (int j = 0; j < 4; j++)
                acc[i][j] = __builtin_amdgcn_mfma_f32_16x16x32_bf16(
                    af[i], bfr[j], acc[i][j], 0, 0, 0);
        __builtin_amdgcn_s_setprio(0);
        __syncthreads();   // protect LDS for next iteration
    }

    // ---- epilogue ----
    #pragma unroll
    for (int i = 0; i < MI; i++) {
        #pragma unroll
        for (int r = 0; r < 4; r++) {
            const int row = wmb + i * 16 + hi * 4 + r;
            if (m0 + row >= cnt) continue;
            if (FC1) {
                const size_t orow = (size_t)(slot0 + row) * IDIM;
                #pragma unroll
                for (int j = 0; j < 4; j++) {
                    const int col = n0 + wnb + j * 16 + lo;
                    const float v = acc[i][j][r] + bias[e * N + col];
                    out_bf[orow + col] = f2b(gelu_tanh(v));
                }
            } else {
                const float g = slot_gate[slot0 + row];
                const size_t orow = (size_t)(slot0 + row) * HDIM;
                #pragma unroll
                for (int j = 0; j < 4; j++) {
                    const int col = n0 + wnb + j * 16 + lo;
                    out_f[orow + col] = g * (acc[i][j][r] + bias[e * N + col]);
                }
            }
        }
    }
}

// ---------------- K6: combine the two slot rows per token --------------------
__global__ __launch_bounds__(256) void k_combine(
    const float* __restrict__ outslot, const int* __restrict__ tok2slot,
    float* __restrict__ out)
{
    const int t = blockIdx.x;
    const int sA = tok2slot[2 * t], sB = tok2slot[2 * t + 1];
    const float* ra = outslot + (size_t)sA * HDIM;
    const float* rb = outslot + (size_t)sB * HDIM;
    float* ro = out + (size_t)t * HDIM;
    #pragma unroll
    for (int c = 0; c < 2; c++) {
        const int i = c * 1024 + threadIdx.x * 4;
        const float4 a = *reinterpret_cast<const float4*>(ra + i);
        const float4 b = *reinterpret_cast<const float4*>(rb + i);
        float4 o; o.x = a.x + b.x; o.y = a.y + b.y; o.z = a.z + b.z; o.w = a.w + b.w;
        *reinterpret_cast<float4*>(ro + i) = o;
    }
}

extern "C" void kernel_launch(void* const* d_in, const int* in_sizes, int n_in,
                              void* d_out, int out_size, void* d_ws, size_t ws_size,
                              hipStream_t stream)
{
    const float* x  = (const float*)d_in[0];
    const float* gw = (const float*)d_in[1];
    const float* gb = (const float*)d_in[2];
    const float* w1 = (const float*)d_in[3];
    const float* b1 = (const float*)d_in[4];
    const float* w2 = (const float*)d_in[5];
    const float* b2 = (const float*)d_in[6];
    const float* al = (const float*)d_in[7];
    float* out = (float*)d_out;

    char* ws = (char*)d_ws;
    unsigned short* xb = (unsigned short*)ws;                    // 8 MB
    unsigned short* h1 = (unsigned short*)(ws + 8388608);        // 64 MB
    float* outslot     = (float*)(ws + 75497472);                // 32 MB
    char* meta = ws + 109051904;
    int* counts     = (int*)meta;
    int* offsets    = (int*)(meta + 32);
    int* cursors    = (int*)(meta + 64);
    int* slot_token = (int*)(meta + 256);
    int* tok2slot   = (int*)(meta + 256 + 16384);
    int* top_e      = (int*)(meta + 256 + 32768);
    float* slot_gate= (float*)(meta + 256 + 49152);
    float* top_g    = (float*)(meta + 256 + 65536);

    hipMemsetAsync(counts, 0, 32, stream);
    k_gate<<<dim3(T_TOK / 4), dim3(256), 0, stream>>>(x, gw, gb, al, xb, counts, top_e, top_g);
    k_scan<<<dim3(1), dim3(64), 0, stream>>>(counts, offsets, cursors);
    k_append<<<dim3(T_TOK / 256), dim3(256), 0, stream>>>(top_e, top_g, cursors,
                                                          slot_token, slot_gate, tok2slot);
    k_gemm<true><<<dim3(NEXP * (IDIM / 128) * (T_TOK / 128)), dim3(256), 0, stream>>>(
        xb, w1, b1, counts, offsets, slot_token, slot_gate, h1, nullptr);
    k_gemm<false><<<dim3(NEXP * (HDIM / 64) * (T_TOK / 128)), dim3(256), 0, stream>>>(
        h1, w2, b2, counts, offsets, slot_token, slot_gate, nullptr, outslot);
    k_combine<<<dim3(T_TOK), dim3(256), 0, stream>>>(outslot, tok2slot, out);
}

// Round 8
// 1004.026 us; speedup vs baseline: 1.0668x; 1.0668x over previous
//
#include <hip/hip_runtime.h>
#include <hip/hip_bf16.h>
#include <cstdint>

#define T_TOK 2048
#define HDIM  2048
#define IDIM  8192
#define NEXP  8

typedef short s16x8 __attribute__((ext_vector_type(8)));
typedef float f32x4 __attribute__((ext_vector_type(4)));
typedef const __attribute__((address_space(1))) uint32_t gbl_u32;
typedef __attribute__((address_space(3))) uint32_t lds_u32;

__device__ __forceinline__ unsigned short f2b(float f) {
    union { float f; unsigned u; } c; c.f = f;
    unsigned r = (c.u + 0x7fffu + ((c.u >> 16) & 1u)) >> 16;
    return (unsigned short)r;
}

__device__ __forceinline__ float gelu_tanh(float v) {
    float u = 0.7978845608028654f * (v + 0.044715f * v * v * v);
    return 0.5f * v * (1.0f + tanhf(u));
}

// ---------------- K1: gate (logits fp32, softmax, top-2) + cast x -> bf16 ----
__global__ __launch_bounds__(256) void k_gate(
    const float* __restrict__ x, const float* __restrict__ gw,
    const float* __restrict__ gb, const float* __restrict__ alpha,
    unsigned short* __restrict__ xb, int* __restrict__ counts,
    int* __restrict__ top_e, float* __restrict__ top_g)
{
    const int wave = threadIdx.x >> 6;
    const int lane = threadIdx.x & 63;
    const int t = blockIdx.x * 4 + wave;
    if (t >= T_TOK) return;

    float acc[8];
    #pragma unroll
    for (int e = 0; e < 8; e++) acc[e] = 0.f;

    const float* xrow = x + (size_t)t * HDIM;
    unsigned short* xbrow = xb + (size_t)t * HDIM;

    #pragma unroll
    for (int c = 0; c < 8; c++) {
        const int h0 = c * 256 + lane * 4;
        const float4 xv = *reinterpret_cast<const float4*>(xrow + h0);
        ushort4 u;
        u.x = f2b(xv.x); u.y = f2b(xv.y); u.z = f2b(xv.z); u.w = f2b(xv.w);
        *reinterpret_cast<ushort4*>(xbrow + h0) = u;
        const float xs[4] = {xv.x, xv.y, xv.z, xv.w};
        #pragma unroll
        for (int r = 0; r < 4; r++) {
            const float4 g0 = *reinterpret_cast<const float4*>(gw + (size_t)(h0 + r) * 8);
            const float4 g1 = *reinterpret_cast<const float4*>(gw + (size_t)(h0 + r) * 8 + 4);
            acc[0] += xs[r] * g0.x; acc[1] += xs[r] * g0.y;
            acc[2] += xs[r] * g0.z; acc[3] += xs[r] * g0.w;
            acc[4] += xs[r] * g1.x; acc[5] += xs[r] * g1.y;
            acc[6] += xs[r] * g1.z; acc[7] += xs[r] * g1.w;
        }
    }
    #pragma unroll
    for (int e = 0; e < 8; e++) {
        #pragma unroll
        for (int off = 32; off > 0; off >>= 1)
            acc[e] += __shfl_xor(acc[e], off);
        acc[e] += gb[e];
    }
    float m = acc[0];
    #pragma unroll
    for (int e = 1; e < 8; e++) m = fmaxf(m, acc[e]);
    float Z = 0.f;
    #pragma unroll
    for (int e = 0; e < 8; e++) Z += expf(acc[e] - m);
    int e0 = 0; float b0 = acc[0];
    #pragma unroll
    for (int e = 1; e < 8; e++) if (acc[e] > b0) { b0 = acc[e]; e0 = e; }
    int e1 = -1; float b1 = -1e30f;
    #pragma unroll
    for (int e = 0; e < 8; e++) if (e != e0 && acc[e] > b1) { b1 = acc[e]; e1 = e; }

    if (lane == 0) {
        const float s0 = expf(b0 - m) / Z * alpha[e0];
        const float s1 = expf(b1 - m) / Z * alpha[e1];
        top_e[2 * t]     = e0; top_e[2 * t + 1] = e1;
        top_g[2 * t]     = s0; top_g[2 * t + 1] = s1;
        atomicAdd(&counts[e0], 1);
        atomicAdd(&counts[e1], 1);
    }
}

// ---------------- K2: exclusive scan of 8 counts -----------------------------
__global__ void k_scan(const int* __restrict__ counts, int* __restrict__ offsets,
                       int* __restrict__ cursors)
{
    if (threadIdx.x == 0) {
        int off = 0;
        for (int e = 0; e < NEXP; e++) {
            offsets[e] = off; cursors[e] = off; off += counts[e];
        }
    }
}

// ---------------- K3: append tokens to per-expert compact slot lists ---------
__global__ __launch_bounds__(256) void k_append(
    const int* __restrict__ top_e, const float* __restrict__ top_g,
    int* __restrict__ cursors, int* __restrict__ slot_token,
    float* __restrict__ slot_gate, int* __restrict__ tok2slot)
{
    const int t = blockIdx.x * 256 + threadIdx.x;
    if (t >= T_TOK) return;
    #pragma unroll
    for (int k = 0; k < 2; k++) {
        const int e = top_e[2 * t + k];
        const int slot = atomicAdd(&cursors[e], 1);
        slot_token[slot] = t;
        slot_gate[slot]  = top_g[2 * t + k];
        tok2slot[2 * t + k] = slot;
    }
}

// ---------------- K-conv: transpose-convert W[KW][NW] f32 -> WT[NW][KW] bf16 -
// All 8 experts (blockIdx.z). 128k x 64n tiles. Verified in R5.
__global__ __launch_bounds__(256) void k_convT(
    const float* __restrict__ W, unsigned short* __restrict__ WT,
    int KW, int NW)
{
    const int e  = blockIdx.z;
    const int k0 = blockIdx.y * 128;
    const int n0 = blockIdx.x * 64;
    const float* src = W + (size_t)e * KW * NW;
    unsigned short* dst = WT + (size_t)e * KW * NW;

    __shared__ unsigned short lt[64][136];

    const int tid = threadIdx.x;
    const int n4 = (tid & 15) * 4;
    #pragma unroll
    for (int r = 0; r < 8; r++) {
        const int kr = (tid >> 4) + r * 16;
        const float4 v = *reinterpret_cast<const float4*>(
            src + (size_t)(k0 + kr) * NW + n0 + n4);
        lt[n4 + 0][kr] = f2b(v.x);
        lt[n4 + 1][kr] = f2b(v.y);
        lt[n4 + 2][kr] = f2b(v.z);
        lt[n4 + 3][kr] = f2b(v.w);
    }
    __syncthreads();
    const int n  = tid >> 2;
    const int kc = (tid & 3) * 32;
    unsigned short* orow = dst + (size_t)(n0 + n) * KW + k0 + kc;
    const uint4* lsrc = reinterpret_cast<const uint4*>(&lt[n][kc]);
    #pragma unroll
    for (int i = 0; i < 4; i++)
        *reinterpret_cast<uint4*>(orow + i * 8) = lsrc[i];
}

// ---------------- K4/K5: m97-structure bf16 GEMM (glds both operands) --------
// A: bf16 [M][K] rows (fc1: gathered tokens; fc2: slot rows), 128 rows.
// B: bf16 [N][K] rows (pre-transposed weights), BN rows (128 fc1 / 64 fc2).
// Both staged via global_load_lds into [rows][64] LDS, chunk-XOR involution.
// FC1: 4 waves 2x2 (64x64 each).  FC2: 4 waves 4x1 (32x64 each).
template<bool FC1>
__global__ __launch_bounds__(256, 4) void k_gemm(
    const unsigned short* __restrict__ Abase,
    const unsigned short* __restrict__ WT,
    const float* __restrict__ bias,
    const int* __restrict__ counts,
    const int* __restrict__ offsets,
    const int* __restrict__ slot_token,
    const float* __restrict__ slot_gate,
    unsigned short* __restrict__ out_bf,
    float* __restrict__ out_f)
{
    constexpr int N  = FC1 ? IDIM : HDIM;
    constexpr int K  = FC1 ? HDIM : IDIM;
    constexpr int BN = FC1 ? 128 : 64;
    constexpr int NT = N / BN;
    constexpr int MT = T_TOK / 128;
    constexpr int NK = K / 64;
    constexpr int MI = FC1 ? 4 : 2;
    constexpr int BITS = BN / 32;          // B-staging glds per thread (4 / 2)

    // bijective XCD swizzle (nwg % 8 == 0), m fastest: one expert per XCD.
    constexpr int nwg = NEXP * NT * MT;
    constexpr int cpx = nwg >> 3;
    const int bid = blockIdx.x;
    const int wg  = (bid & 7) * cpx + (bid >> 3);
    const int e   = wg / (NT * MT);
    const int rem = wg - e * (NT * MT);
    const int nb  = rem / MT;
    const int mb  = rem - nb * MT;

    const int cnt = counts[e];
    const int m0  = mb * 128;
    if (m0 >= cnt) return;
    const int moff  = offsets[e];
    const int n0    = nb * BN;
    const int slot0 = moff + m0;

    __shared__ short As[128 * 64];   // 16 KB, chunk-XOR (ch ^= row&7)
    __shared__ short Bs[BN * 64];    // 16/8 KB, same scheme (rows = n)

    const int tid  = threadIdx.x;
    const int lane = tid & 63, wave = tid >> 6;
    const int lo = lane & 15, hi = lane >> 4;
    const int wmb = FC1 ? (wave >> 1) * 64 : wave * 32;
    const int wnb = FC1 ? (wave & 1) * 64 : 0;

    // staging geometry: row (tid>>3)+it*32, 16B chunk tid&7, involution ch^=(row&7)
    const unsigned short* asrc[4];
    #pragma unroll
    for (int it = 0; it < 4; it++) {
        const int row = (tid >> 3) + it * 32;
        int tok;
        if (FC1) tok = (m0 + row < cnt) ? slot_token[moff + m0 + row] : 0;
        else     tok = slot0 + ((m0 + row < cnt) ? row : 0);
        asrc[it] = Abase + (size_t)tok * K;
    }
    const unsigned short* bsrc[BITS];
    #pragma unroll
    for (int it = 0; it < BITS; it++) {
        const int row = (tid >> 3) + it * 32;
        bsrc[it] = WT + (size_t)e * (size_t)N * K + (size_t)(n0 + row) * K;
    }
    const int achunk = tid & 7;

    f32x4 acc[MI][4];
    #pragma unroll
    for (int i = 0; i < MI; i++)
        #pragma unroll
        for (int j = 0; j < 4; j++) acc[i][j] = (f32x4)0.f;

    for (int t = 0; t < NK; t++) {
        const int kk = t * 64;
        #pragma unroll
        for (int it = 0; it < 4; it++) {
            const int row = (tid >> 3) + it * 32;
            const int sc  = achunk ^ (row & 7);
            __builtin_amdgcn_global_load_lds(
                (gbl_u32*)(asrc[it] + kk + sc * 8),
                (lds_u32*)(As + (tid + it * 256) * 8), 16, 0, 0);
        }
        #pragma unroll
        for (int it = 0; it < BITS; it++) {
            const int row = (tid >> 3) + it * 32;
            const int sc  = achunk ^ (row & 7);
            __builtin_amdgcn_global_load_lds(
                (gbl_u32*)(bsrc[it] + kk + sc * 8),
                (lds_u32*)(Bs + (tid + it * 256) * 8), 16, 0, 0);
        }
        __syncthreads();   // drains vmcnt: tiles visible
        #pragma unroll
        for (int ks = 0; ks < 2; ks++) {
            s16x8 af[MI], bfr[4];
            #pragma unroll
            for (int i = 0; i < MI; i++) {
                const int arow = wmb + i * 16 + lo;
                const int ch = (ks * 4 + hi) ^ (arow & 7);
                af[i] = *reinterpret_cast<const s16x8*>(As + arow * 64 + ch * 8);
            }
            #pragma unroll
            for (int j = 0; j < 4; j++) {
                const int brow = wnb + j * 16 + lo;
                const int ch = (ks * 4 + hi) ^ (brow & 7);
                bfr[j] = *reinterpret_cast<const s16x8*>(Bs + brow * 64 + ch * 8);
            }
            __builtin_amdgcn_s_setprio(1);
            #pragma unroll
            for (int i = 0; i < MI; i++)
                #pragma unroll
                for (int j = 0; j < 4; j++)
                    acc[i][j] = __builtin_amdgcn_mfma_f32_16x16x32_bf16(
                        af[i], bfr[j], acc[i][j], 0, 0, 0);
            __builtin_amdgcn_s_setprio(0);
        }
        __syncthreads();   // protect LDS for next stage
    }

    // ---- epilogue ----
    #pragma unroll
    for (int i = 0; i < MI; i++) {
        #pragma unroll
        for (int r = 0; r < 4; r++) {
            const int row = wmb + i * 16 + hi * 4 + r;
            if (m0 + row >= cnt) continue;
            if (FC1) {
                const size_t orow = (size_t)(slot0 + row) * IDIM;
                #pragma unroll
                for (int j = 0; j < 4; j++) {
                    const int col = n0 + wnb + j * 16 + lo;
                    const float v = acc[i][j][r] + bias[e * N + col];
                    out_bf[orow + col] = f2b(gelu_tanh(v));
                }
            } else {
                const float g = slot_gate[slot0 + row];
                const size_t orow = (size_t)(slot0 + row) * HDIM;
                #pragma unroll
                for (int j = 0; j < 4; j++) {
                    const int col = n0 + wnb + j * 16 + lo;
                    out_f[orow + col] = g * (acc[i][j][r] + bias[e * N + col]);
                }
            }
        }
    }
}

// ---------------- K6: combine the two slot rows per token --------------------
__global__ __launch_bounds__(256) void k_combine(
    const float* __restrict__ outslot, const int* __restrict__ tok2slot,
    float* __restrict__ out)
{
    const int t = blockIdx.x;
    const int sA = tok2slot[2 * t], sB = tok2slot[2 * t + 1];
    const float* ra = outslot + (size_t)sA * HDIM;
    const float* rb = outslot + (size_t)sB * HDIM;
    float* ro = out + (size_t)t * HDIM;
    #pragma unroll
    for (int c = 0; c < 2; c++) {
        const int i = c * 1024 + threadIdx.x * 4;
        const float4 a = *reinterpret_cast<const float4*>(ra + i);
        const float4 b = *reinterpret_cast<const float4*>(rb + i);
        float4 o; o.x = a.x + b.x; o.y = a.y + b.y; o.z = a.z + b.z; o.w = a.w + b.w;
        *reinterpret_cast<float4*>(ro + i) = o;
    }
}

extern "C" void kernel_launch(void* const* d_in, const int* in_sizes, int n_in,
                              void* d_out, int out_size, void* d_ws, size_t ws_size,
                              hipStream_t stream)
{
    const float* x  = (const float*)d_in[0];
    const float* gw = (const float*)d_in[1];
    const float* gb = (const float*)d_in[2];
    const float* w1 = (const float*)d_in[3];
    const float* b1 = (const float*)d_in[4];
    const float* w2 = (const float*)d_in[5];
    const float* b2 = (const float*)d_in[6];
    const float* al = (const float*)d_in[7];
    float* out = (float*)d_out;

    // ws layout (harness poisons full ws: observed 2 GiB fill -> plenty)
    char* ws = (char*)d_ws;
    unsigned short* xb  = (unsigned short*)ws;                     // 8 MB
    unsigned short* h1  = (unsigned short*)(ws + 8388608);         // 64 MB
    float* outslot      = (float*)(ws + 75497472);                 // 32 MB
    unsigned short* wT1 = (unsigned short*)(ws + 109051904);       // 256 MB
    unsigned short* wT2 = (unsigned short*)(ws + 377487360);       // 256 MB
    char* meta = ws + 645922816;
    int* counts     = (int*)meta;
    int* offsets    = (int*)(meta + 32);
    int* cursors    = (int*)(meta + 64);
    int* slot_token = (int*)(meta + 256);
    int* tok2slot   = (int*)(meta + 256 + 16384);
    int* top_e      = (int*)(meta + 256 + 32768);
    float* slot_gate= (float*)(meta + 256 + 49152);
    float* top_g    = (float*)(meta + 256 + 65536);

    hipMemsetAsync(counts, 0, 32, stream);
    k_gate<<<dim3(T_TOK / 4), dim3(256), 0, stream>>>(x, gw, gb, al, xb, counts, top_e, top_g);
    k_scan<<<dim3(1), dim3(64), 0, stream>>>(counts, offsets, cursors);
    k_append<<<dim3(T_TOK / 256), dim3(256), 0, stream>>>(top_e, top_g, cursors,
                                                          slot_token, slot_gate, tok2slot);
    // transpose-convert all experts' weights to bf16 [N][K]
    k_convT<<<dim3(IDIM / 64, HDIM / 128, NEXP), dim3(256), 0, stream>>>(w1, wT1, HDIM, IDIM);
    k_gemm<true><<<dim3(NEXP * (IDIM / 128) * (T_TOK / 128)), dim3(256), 0, stream>>>(
        xb, wT1, b1, counts, offsets, slot_token, slot_gate, h1, nullptr);
    k_convT<<<dim3(HDIM / 64, IDIM / 128, NEXP), dim3(256), 0, stream>>>(w2, wT2, IDIM, HDIM);
    k_gemm<false><<<dim3(NEXP * (HDIM / 64) * (T_TOK / 128)), dim3(256), 0, stream>>>(
        h1, wT2, b2, counts, offsets, slot_token, slot_gate, nullptr, outslot);
    k_combine<<<dim3(T_TOK), dim3(256), 0, stream>>>(outslot, tok2slot, out);
}